// Round 6
// baseline (925.613 us; speedup 1.0000x reference)
//
#include <hip/hip_runtime.h>

// SNNConv2d — bit-exact replication of XLA-CPU fp32 reference.
// Hypothesis H1: XLA CPU canonicalizes NCHW->NHWC and calls Eigen conv
// (im2col + sgemm). Per output element the accumulation is a sequential
// single-accumulator FMA fold over k ascending in (kh, kw, ci) order.
// Padding taps are exact fma-identities (product == 0) -> skipped.
// Membrane recurrence in fp32: mem = round(round(mem + c) * 0.9f);
// spike = mem >= 0.25f; reset exact. GPU v_fma_f32 == x86 vfmadd (IEEE).

#define BB   8
#define CIN  16
#define HH   64
#define WW   64
#define TT   32
#define COUT 32

__global__ void snn_fp32_eigen(const float* __restrict__ x,
                               const float* __restrict__ wgt,
                               float* __restrict__ out) {
    // block = 256 threads = 32 co x 8 w ; grid = (W/8, H, B)
    const int tid = threadIdx.x;
    const int co  = tid & 31;
    const int wi  = tid >> 5;
    const int w   = blockIdx.x * 8 + wi;
    const int h   = blockIdx.y;
    const int b   = blockIdx.z;

    float acc[TT];
#pragma unroll
    for (int t = 0; t < TT; ++t) acc[t] = 0.0f;

    // k ascending in (kh, kw, ci): kh outer, kw middle, ci inner.
    for (int kh = 0; kh < 3; ++kh) {
        const int hs = h + kh - 1;
        if (hs < 0 || hs >= HH) continue;          // fma with 0 product == identity
        for (int kw = 0; kw < 3; ++kw) {
            const int ws = w + kw - 1;
            if (ws < 0 || ws >= WW) continue;
            for (int ci = 0; ci < CIN; ++ci) {
                const float wv = wgt[((co * CIN + ci) * 3 + kh) * 3 + kw];
                const float* xp = x + (((b * CIN + ci) * HH + hs) * WW + ws) * TT;
#pragma unroll
                for (int t = 0; t < TT; ++t)
                    acc[t] = fmaf(xp[t], wv, acc[t]);   // single-rounded, fixed order
            }
        }
    }

    // membrane recurrence in fp32, exact op-for-op with the reference
    float* op = out + (((b * COUT + co) * HH + h) * WW + w) * TT;
    float mem = 0.0f;
#pragma unroll
    for (int t = 0; t < TT; ++t) {
        mem = (mem + acc[t]) * 0.9f;   // two separately-rounded fp32 ops
        if (mem >= 0.25f) { op[t] = 1.0f; mem = 0.0f; }
        else              { op[t] = 0.0f; }
    }
}

extern "C" void kernel_launch(void* const* d_in, const int* in_sizes, int n_in,
                              void* d_out, int out_size, void* d_ws, size_t ws_size,
                              hipStream_t stream) {
    const float* x   = (const float*)d_in[0];   // 8*16*64*64*32
    const float* wgt = (const float*)d_in[1];   // 32*16*3*3
    float* out = (float*)d_out;                 // 8*32*64*64*32

    dim3 grid(WW / 8, HH, BB);   // (8, 64, 8)
    dim3 block(256);
    snn_fp32_eigen<<<grid, block, 0, stream>>>(x, wgt, out);
}

// Round 8
// 466.813 us; speedup vs baseline: 1.9828x; 1.9828x over previous
//
#include <hip/hip_runtime.h>
#include <hip/hip_fp16.h>

// SNNConv2d — bit-exact XLA-CPU fp32 replication (H1, verified round 6),
// now LDS-staged. Invariant preserved: per output element the accumulator
// folds taps ascending in (kh, kw, ci) with single-rounded fp32 FMA;
// membrane = (mem+c)*0.9f (two rounded ops), spike = mem>=0.25f, exact reset.
// x is binary {0,1} -> exact in f16; fma(f16->f32 promote, w, acc) is
// bit-identical to fma(f32 x, w, acc). OOB taps staged as 0: fma(+-0,w,acc)
// == acc for all sign cases -> identical to skipping.

#define BB   8
#define CIN  16
#define HH   64
#define WW   64
#define TT   32
#define COUT 32

__global__ __launch_bounds__(256)
void snn_lds(const float* __restrict__ x,
             const float* __restrict__ wgt,
             float* __restrict__ out) {
    const int tid = threadIdx.x;
    const int co  = tid & 31;
    const int wi  = tid >> 5;
    const int w0  = blockIdx.x * 8;
    const int h   = blockIdx.y;
    const int b   = blockIdx.z;
    const int w   = w0 + wi;

    // x tile: rows r=0..2 (h-1..h+1) x cols wc=0..9 (w0-1..w0+8) x ci x t
    __shared__ __half2 s_x[3 * 10 * CIN * (TT / 2)];   // 30720 B, [r][wc][ci][t2]
    __shared__ float   s_w[144 * 32];                  // 18432 B, [tau][co]

    // ---- stage weights: tau = (kh*3+kw)*16 + ci ; wgt[co][ci][kh][kw] ----
    for (int e = tid; e < 144 * 32; e += 256) {
        const int cc  = e & 31;
        const int tau = e >> 5;
        const int ci  = tau & 15;
        const int khw = tau >> 4;            // kh*3+kw
        s_w[e] = wgt[cc * 144 + ci * 9 + khw];
    }

    // ---- stage x as f16 (exact for binary): 7680 half2 words ----
    for (int e = tid; e < 3 * 10 * CIN * (TT / 2); e += 256) {   // 30 iters
        const int t2 = e & 15;
        const int ci = (e >> 4) & 15;
        const int q  = e >> 8;               // 0..29
        const int wc = q % 10;
        const int r  = q / 10;
        const int hs = h + r - 1;
        const int ws = w0 + wc - 1;
        __half2 hv = __floats2half2_rn(0.0f, 0.0f);
        if ((unsigned)hs < HH && (unsigned)ws < WW) {
            const float2 v = *(const float2*)(
                x + ((long)((b * CIN + ci) * HH + hs) * WW + ws) * TT + t2 * 2);
            hv = __floats2half2_rn(v.x, v.y);
        }
        s_x[e] = hv;
    }
    __syncthreads();

    float acc[TT];
#pragma unroll
    for (int t = 0; t < TT; ++t) acc[t] = 0.0f;

    // ---- main loop: fold order (kh, kw, ci) ascending — FROZEN ----
    for (int kh = 0; kh < 3; ++kh) {
        for (int kw = 0; kw < 3; ++kw) {
            const __half2* xr = s_x + (kh * 10 + wi + kw) * (CIN * 16);
            const float*   wr = s_w + (kh * 3 + kw) * (CIN * 32) + co;
#pragma unroll
            for (int ci = 0; ci < CIN; ++ci) {
                const float wv = wr[ci * 32];
#pragma unroll
                for (int t2 = 0; t2 < 16; ++t2) {
                    const __half2 h2 = xr[ci * 16 + t2];
                    acc[2 * t2]     = fmaf(__low2float(h2),  wv, acc[2 * t2]);
                    acc[2 * t2 + 1] = fmaf(__high2float(h2), wv, acc[2 * t2 + 1]);
                }
            }
        }
    }

    // ---- membrane recurrence + spike write (identical to passing kernel) ----
    float* op = out + ((long)((b * COUT + co) * HH + h) * WW + w) * TT;
    float mem = 0.0f;
#pragma unroll
    for (int t4 = 0; t4 < TT; t4 += 4) {
        float4 v;
        float* vp = &v.x;
#pragma unroll
        for (int j = 0; j < 4; ++j) {
            mem = (mem + acc[t4 + j]) * 0.9f;
            const bool sp = (mem >= 0.25f);
            vp[j] = sp ? 1.0f : 0.0f;
            if (sp) mem = 0.0f;
        }
        *reinterpret_cast<float4*>(op + t4) = v;
    }
}

extern "C" void kernel_launch(void* const* d_in, const int* in_sizes, int n_in,
                              void* d_out, int out_size, void* d_ws, size_t ws_size,
                              hipStream_t stream) {
    const float* x   = (const float*)d_in[0];   // 8*16*64*64*32
    const float* wgt = (const float*)d_in[1];   // 32*16*3*3
    float* out = (float*)d_out;                 // 8*32*64*64*32

    dim3 grid(WW / 8, HH, BB);   // (8, 64, 8)
    dim3 block(256);
    snn_lds<<<grid, block, 0, stream>>>(x, wgt, out);
}

// Round 10
// 281.163 us; speedup vs baseline: 3.2921x; 1.6603x over previous
//
#include <hip/hip_runtime.h>

// SNNConv2d — bit-exact XLA-CPU fp32 replication (verified r6/r8).
// FROZEN invariant: per output element, acc folds taps ascending (kh,kw,ci)
// with single-rounded fp32 FMA; membrane = (mem+c)*0.9f (two rounded ops);
// spike = mem >= 0.25f; exact reset. OOB taps = exact-zero products.
//
// This round: t-on-lanes. Wave = 32t x 2w; thread holds acc[co=0..31].
// Per tap: one per-lane f32 x load (2 cache lines/wave) + 32 FMA with a
// wave-uniform weight (repacked wT in d_ws -> scalar loads). 1 VALU op/MAC.
// Epilogue: LDS transpose (t back into registers) + identical membrane code.

#define BB   8
#define CIN  16
#define HH   64
#define WW   64
#define TT   32
#define COUT 32
#define HWT  (HH * WW * TT)

// wT[tau][co], tau = (kh*3+kw)*16 + ci
__global__ void repack_w(const float* __restrict__ wgt, float* __restrict__ wT) {
    const int e = blockIdx.x * 256 + threadIdx.x;
    if (e < 144 * 32) {
        const int co  = e & 31;
        const int tau = e >> 5;
        const int ci  = tau & 15;
        const int khw = tau >> 4;
        wT[tau * 32 + co] = wgt[co * 144 + ci * 9 + khw];
    }
}

__global__ __launch_bounds__(256)
void snn_main(const float* __restrict__ x, const float* __restrict__ wT,
              float* __restrict__ out) {
    const int tid  = threadIdx.x;
    const int lane = tid & 63;
    const int t    = lane & 31;          // time on lanes
    const int wi   = (tid >> 5);         // 0..7 (wave = 2 consecutive wi)
    const int w0   = blockIdx.x * 8;
    const int h    = blockIdx.y;
    const int b    = blockIdx.z;
    const int w    = w0 + wi;

    float acc[COUT];
#pragma unroll
    for (int c = 0; c < COUT; ++c) acc[c] = 0.0f;

    // ---- main loop: fold order (kh, kw, ci) ascending — FROZEN ----
#pragma unroll
    for (int kh = 0; kh < 3; ++kh) {
        const int hs = h + kh - 1;
        if ((unsigned)hs >= HH) continue;              // wave-uniform skip
#pragma unroll
        for (int kw = 0; kw < 3; ++kw) {
            const int ws    = w + kw - 1;
            const bool ok   = (unsigned)ws < WW;       // edge lanes only
            const int  wsc  = ok ? ws : 0;             // clamped addr
            const float* xp = x + ((b * CIN * HH + hs) * WW + wsc) * TT + t;
#pragma unroll
            for (int ci = 0; ci < CIN; ++ci) {
                float xv = xp[ci * HWT];               // per-lane f32
                xv = ok ? xv : 0.0f;                   // exact-zero product OOB
                const float* wr = wT + ((kh * 3 + kw) * 16 + ci) * 32;  // uniform
#pragma unroll
                for (int c = 0; c < COUT; ++c)
                    acc[c] = fmaf(xv, wr[c], acc[c]);  // single-rounded chain
            }
        }
    }

    // ---- transpose via LDS: [co*8+wi][36-pad] f32 rows ----
    __shared__ float s_tr[256 * 36];                   // 36864 B
#pragma unroll
    for (int c = 0; c < COUT; ++c)
        s_tr[(c * 8 + wi) * 36 + t] = acc[c];
    __syncthreads();

    // thread -> (co2, wi2); reads its 32 t values contiguously
    const int co2 = tid >> 3;
    const int wi2 = tid & 7;
    const float* rr = s_tr + (co2 * 8 + wi2) * 36;

    float* op = out + (((b * COUT + co2) * HH + h) * WW + (w0 + wi2)) * TT;
    float mem = 0.0f;
#pragma unroll
    for (int t4 = 0; t4 < TT; t4 += 4) {
        const float4 q = *reinterpret_cast<const float4*>(rr + t4);
        const float cv[4] = {q.x, q.y, q.z, q.w};
        float4 o;
        float* vp = &o.x;
#pragma unroll
        for (int j = 0; j < 4; ++j) {
            mem = (mem + cv[j]) * 0.9f;                // two rounded ops — FROZEN
            const bool sp = (mem >= 0.25f);
            vp[j] = sp ? 1.0f : 0.0f;
            if (sp) mem = 0.0f;
        }
        *reinterpret_cast<float4*>(op + t4) = o;
    }
}

extern "C" void kernel_launch(void* const* d_in, const int* in_sizes, int n_in,
                              void* d_out, int out_size, void* d_ws, size_t ws_size,
                              hipStream_t stream) {
    const float* x   = (const float*)d_in[0];   // 8*16*64*64*32
    const float* wgt = (const float*)d_in[1];   // 32*16*3*3
    float* out = (float*)d_out;                 // 8*32*64*64*32
    float* wT  = (float*)d_ws;                  // 144*32 f32 = 18432 B scratch

    repack_w<<<18, 256, 0, stream>>>(wgt, wT);

    dim3 grid(WW / 8, HH, BB);                  // (8, 64, 8)
    snn_main<<<grid, dim3(256), 0, stream>>>(x, wT, out);
}

// Round 11
// 278.034 us; speedup vs baseline: 3.3291x; 1.0113x over previous
//
#include <hip/hip_runtime.h>

// SNNConv2d — bit-exact XLA-CPU fp32 replication (verified r6/r8/r10).
// FROZEN: per output element, acc folds taps ascending (kh,kw,ci) with
// single-rounded fp32 FMA; membrane = (mem+c)*0.9f (two rounded ops);
// spike = mem >= 0.25f; exact reset; OOB taps = exact-zero products.
//
// r11: (1) f32x2 accumulators -> v_pk_fma_f32 (2 independent chains/instr,
// per-component IEEE fma => bit-exact). (2) epilogue LDS halved to 18.4 KB
// (two-pass transpose) + __launch_bounds__(256,8) -> 8 blocks/CU.

#define BB   8
#define CIN  16
#define HH   64
#define WW   64
#define TT   32
#define COUT 32
#define HWT  (HH * WW * TT)

typedef float f32x2 __attribute__((ext_vector_type(2)));

// wT[tau][co], tau = (kh*3+kw)*16 + ci
__global__ void repack_w(const float* __restrict__ wgt, float* __restrict__ wT) {
    const int e = blockIdx.x * 256 + threadIdx.x;
    if (e < 144 * 32) {
        const int co  = e & 31;
        const int tau = e >> 5;
        const int ci  = tau & 15;
        const int khw = tau >> 4;
        wT[tau * 32 + co] = wgt[co * 144 + ci * 9 + khw];
    }
}

__global__ __launch_bounds__(256, 8)
void snn_main(const float* __restrict__ x, const float* __restrict__ wT,
              float* __restrict__ out) {
    const int tid = threadIdx.x;
    const int t   = tid & 31;          // time on lanes
    const int wi  = tid >> 5;          // 0..7
    const int w0  = blockIdx.x * 8;
    const int h   = blockIdx.y;
    const int b   = blockIdx.z;
    const int w   = w0 + wi;

    f32x2 acc2[16];                     // acc2[i] = {acc[2i], acc[2i+1]}
#pragma unroll
    for (int i = 0; i < 16; ++i) acc2[i] = (f32x2){0.0f, 0.0f};

    // ---- main loop: fold order (kh, kw, ci) ascending — FROZEN ----
#pragma unroll
    for (int kh = 0; kh < 3; ++kh) {
        const int hs = h + kh - 1;
        if ((unsigned)hs >= HH) continue;              // wave-uniform skip
#pragma unroll
        for (int kw = 0; kw < 3; ++kw) {
            const int ws  = w + kw - 1;
            const bool ok = (unsigned)ws < WW;         // edge lanes only
            const int wsc = ok ? ws : 0;
            const float* xp  = x + ((b * CIN * HH + hs) * WW + wsc) * TT + t;
            const f32x2* wr2 = (const f32x2*)(wT + (kh * 3 + kw) * (CIN * 32));
#pragma unroll
            for (int ci = 0; ci < CIN; ++ci) {
                float xv = xp[ci * HWT];               // per-lane f32
                xv = ok ? xv : 0.0f;                   // exact-zero product OOB
                const f32x2 xv2 = {xv, xv};
#pragma unroll
                for (int c2 = 0; c2 < 16; ++c2)        // 16 x v_pk_fma_f32
                    acc2[c2] = __builtin_elementwise_fma(xv2, wr2[ci * 16 + c2],
                                                         acc2[c2]);
            }
        }
    }

    // ---- two-pass LDS transpose + membrane scan (18432 B) ----
    __shared__ float s_tr[128 * 36];
#pragma unroll
    for (int p = 0; p < 2; ++p) {
        if (p) __syncthreads();                        // pass-1 reads done
#pragma unroll
        for (int j = 0; j < 16; ++j) {                 // write co = 16p+j
            const int c = 16 * p + j;
            s_tr[(j * 8 + wi) * 36 + t] = acc2[c >> 1][c & 1];
        }
        __syncthreads();
        if (tid < 128) {
            const int j2  = tid >> 3;                  // 0..15
            const int wi2 = tid & 7;
            const int co2 = 16 * p + j2;
            const float* rr = s_tr + tid * 36;
            float* op = out + (((b * COUT + co2) * HH + h) * WW + (w0 + wi2)) * TT;
            float mem = 0.0f;
#pragma unroll
            for (int t4 = 0; t4 < TT; t4 += 4) {
                const float4 q = *reinterpret_cast<const float4*>(rr + t4);
                const float cv[4] = {q.x, q.y, q.z, q.w};
                float4 o;
                float* vp = &o.x;
#pragma unroll
                for (int jj = 0; jj < 4; ++jj) {
                    mem = (mem + cv[jj]) * 0.9f;       // two rounded ops — FROZEN
                    const bool sp = (mem >= 0.25f);
                    vp[jj] = sp ? 1.0f : 0.0f;
                    if (sp) mem = 0.0f;
                }
                *reinterpret_cast<float4*>(op + t4) = o;
            }
        }
    }
}

extern "C" void kernel_launch(void* const* d_in, const int* in_sizes, int n_in,
                              void* d_out, int out_size, void* d_ws, size_t ws_size,
                              hipStream_t stream) {
    const float* x   = (const float*)d_in[0];   // 8*16*64*64*32
    const float* wgt = (const float*)d_in[1];   // 32*16*3*3
    float* out = (float*)d_out;                 // 8*32*64*64*32
    float* wT  = (float*)d_ws;                  // 144*32 f32 = 18432 B scratch

    repack_w<<<18, 256, 0, stream>>>(wgt, wT);

    dim3 grid(WW / 8, HH, BB);                  // (8, 64, 8)
    snn_main<<<grid, dim3(256), 0, stream>>>(x, wT, out);
}

// Round 12
// 264.825 us; speedup vs baseline: 3.4952x; 1.0499x over previous
//
#include <hip/hip_runtime.h>

// SNNConv2d — bit-exact XLA-CPU fp32 replication (verified r6/r8/r10/r11).
// FROZEN: per output element, acc folds taps ascending (kh,kw,ci) with
// single-rounded fp32 FMA; membrane = (mem+c)*0.9f (two rounded ops);
// spike = mem >= 0.25f; exact reset; OOB taps = exact-zero products.
//
// r12: (1) XCD-chunk swizzle — each XCD owns one image b (halo rows L2-hit,
// cuts the 141 MB refetch). (2) launch_bounds(256,6) — 85-reg budget keeps
// accumulators in arch VGPRs and lets v_pk_fma_f32 pairing form.

#define BB   8
#define CIN  16
#define HH   64
#define WW   64
#define TT   32
#define COUT 32
#define HWT  (HH * WW * TT)

typedef float f32x2 __attribute__((ext_vector_type(2)));

// wT[tau][co], tau = (kh*3+kw)*16 + ci
__global__ void repack_w(const float* __restrict__ wgt, float* __restrict__ wT) {
    const int e = blockIdx.x * 256 + threadIdx.x;
    if (e < 144 * 32) {
        const int co  = e & 31;
        const int tau = e >> 5;
        const int ci  = tau & 15;
        const int khw = tau >> 4;
        wT[tau * 32 + co] = wgt[co * 144 + ci * 9 + khw];
    }
}

__global__ __launch_bounds__(256, 6)
void snn_main(const float* __restrict__ x, const float* __restrict__ wT,
              float* __restrict__ out) {
    // XCD-chunk swizzle: HW sends bid to XCD (bid%8); give XCD k the
    // contiguous work chunk [k*512,(k+1)*512) = one full image b.
    const int wk = (blockIdx.x & 7) * 512 + (blockIdx.x >> 3);
    const int b  = wk >> 9;
    const int h  = (wk >> 3) & 63;
    const int w0 = (wk & 7) * 8;

    const int tid = threadIdx.x;
    const int t   = tid & 31;          // time on lanes
    const int wi  = tid >> 5;          // 0..7
    const int w   = w0 + wi;

    f32x2 acc2[16];                     // acc2[i] = {acc[2i], acc[2i+1]}
#pragma unroll
    for (int i = 0; i < 16; ++i) acc2[i] = (f32x2){0.0f, 0.0f};

    // ---- main loop: fold order (kh, kw, ci) ascending — FROZEN ----
#pragma unroll
    for (int kh = 0; kh < 3; ++kh) {
        const int hs = h + kh - 1;
        if ((unsigned)hs >= HH) continue;              // wave-uniform skip
#pragma unroll
        for (int kw = 0; kw < 3; ++kw) {
            const int ws  = w + kw - 1;
            const bool ok = (unsigned)ws < WW;         // edge lanes only
            const int wsc = ok ? ws : 0;
            const float* xp  = x + ((b * CIN * HH + hs) * WW + wsc) * TT + t;
            const f32x2* wr2 = (const f32x2*)(wT + (kh * 3 + kw) * (CIN * 32));
#pragma unroll
            for (int ci = 0; ci < CIN; ++ci) {
                float xv = xp[ci * HWT];               // per-lane f32
                xv = ok ? xv : 0.0f;                   // exact-zero product OOB
                const f32x2 xv2 = {xv, xv};
#pragma unroll
                for (int c2 = 0; c2 < 16; ++c2)        // 16 x v_pk_fma_f32
                    acc2[c2] = __builtin_elementwise_fma(xv2, wr2[ci * 16 + c2],
                                                         acc2[c2]);
            }
        }
    }

    // ---- two-pass LDS transpose + membrane scan (18432 B) ----
    __shared__ float s_tr[128 * 36];
#pragma unroll
    for (int p = 0; p < 2; ++p) {
        if (p) __syncthreads();                        // pass-1 reads done
#pragma unroll
        for (int j = 0; j < 16; ++j) {                 // write co = 16p+j
            const int c = 16 * p + j;
            s_tr[(j * 8 + wi) * 36 + t] = acc2[c >> 1][c & 1];
        }
        __syncthreads();
        if (tid < 128) {
            const int j2  = tid >> 3;                  // 0..15
            const int wi2 = tid & 7;
            const int co2 = 16 * p + j2;
            const float* rr = s_tr + tid * 36;
            float* op = out + (((b * COUT + co2) * HH + h) * WW + (w0 + wi2)) * TT;
            float mem = 0.0f;
#pragma unroll
            for (int t4 = 0; t4 < TT; t4 += 4) {
                const float4 q = *reinterpret_cast<const float4*>(rr + t4);
                const float cv[4] = {q.x, q.y, q.z, q.w};
                float4 o;
                float* vp = &o.x;
#pragma unroll
                for (int jj = 0; jj < 4; ++jj) {
                    mem = (mem + cv[jj]) * 0.9f;       // two rounded ops — FROZEN
                    const bool sp = (mem >= 0.25f);
                    vp[jj] = sp ? 1.0f : 0.0f;
                    if (sp) mem = 0.0f;
                }
                *reinterpret_cast<float4*>(op + t4) = o;
            }
        }
    }
}

extern "C" void kernel_launch(void* const* d_in, const int* in_sizes, int n_in,
                              void* d_out, int out_size, void* d_ws, size_t ws_size,
                              hipStream_t stream) {
    const float* x   = (const float*)d_in[0];   // 8*16*64*64*32
    const float* wgt = (const float*)d_in[1];   // 32*16*3*3
    float* out = (float*)d_out;                 // 8*32*64*64*32
    float* wT  = (float*)d_ws;                  // 144*32 f32 = 18432 B scratch

    repack_w<<<18, 256, 0, stream>>>(wgt, wT);

    snn_main<<<dim3(4096), dim3(256), 0, stream>>>(x, wT, out);
}

// Round 14
// 259.184 us; speedup vs baseline: 3.5713x; 1.0218x over previous
//
#include <hip/hip_runtime.h>

// SNNConv2d — bit-exact XLA-CPU fp32 replication (verified r6/r8/r10-r12).
// FROZEN: per output element, acc folds taps ascending (kh,kw,ci) with
// single-rounded fp32 FMA; membrane = (mem+c)*0.9f (two rounded ops);
// spike = mem >= 0.25f; exact reset; OOB taps = exact-zero products.
//
// r13: explicit MLP — per (kh,kw) tap, batch all 16 ci loads into regs
// before the FMA burst (16 loads in flight vs compiler's ~2).
// launch_bounds(256,4) = 128-reg budget. kw rolled to stay in I-cache.

#define BB   8
#define CIN  16
#define HH   64
#define WW   64
#define TT   32
#define COUT 32
#define HWT  (HH * WW * TT)

typedef float f32x2 __attribute__((ext_vector_type(2)));

// wT[tau][co], tau = (kh*3+kw)*16 + ci
__global__ void repack_w(const float* __restrict__ wgt, float* __restrict__ wT) {
    const int e = blockIdx.x * 256 + threadIdx.x;
    if (e < 144 * 32) {
        const int co  = e & 31;
        const int tau = e >> 5;
        const int ci  = tau & 15;
        const int khw = tau >> 4;
        wT[tau * 32 + co] = wgt[co * 144 + ci * 9 + khw];
    }
}

__global__ __launch_bounds__(256, 4)
void snn_main(const float* __restrict__ x, const float* __restrict__ wT,
              float* __restrict__ out) {
    // XCD-chunk swizzle: XCD k owns work chunk [k*512,(k+1)*512) = image b=k.
    const int wk = (blockIdx.x & 7) * 512 + (blockIdx.x >> 3);
    const int b  = wk >> 9;
    const int h  = (wk >> 3) & 63;
    const int w0 = (wk & 7) * 8;

    const int tid = threadIdx.x;
    const int t   = tid & 31;          // time on lanes
    const int wi  = tid >> 5;          // 0..7
    const int w   = w0 + wi;

    f32x2 acc2[16];                     // acc2[i] = {acc[2i], acc[2i+1]}
#pragma unroll
    for (int i = 0; i < 16; ++i) acc2[i] = (f32x2){0.0f, 0.0f};

    // ---- main loop: fold order (kh, kw, ci) ascending — FROZEN ----
#pragma unroll
    for (int kh = 0; kh < 3; ++kh) {
        const int hs = h + kh - 1;
        if ((unsigned)hs >= HH) continue;              // wave-uniform skip
        const float* rowp = x + (b * CIN * HH + hs) * (WW * TT) + t;
        for (int kw = 0; kw < 3; ++kw) {               // rolled: I-cache
            const int ws  = w + kw - 1;
            const bool ok = (unsigned)ws < WW;         // edge lanes only
            const int wsc = ok ? ws : 0;               // clamped (in-bounds)
            const float* xp = rowp + wsc * TT;

            float xv[16];                              // 16 loads in flight
#pragma unroll
            for (int ci = 0; ci < CIN; ++ci)
                xv[ci] = xp[ci * HWT];
#pragma unroll
            for (int ci = 0; ci < CIN; ++ci)
                xv[ci] = ok ? xv[ci] : 0.0f;           // exact-zero OOB product

            const f32x2* wr2 = (const f32x2*)(wT + (kh * 3 + kw) * (CIN * 32));
#pragma unroll
            for (int ci = 0; ci < CIN; ++ci) {
                const f32x2 xv2 = {xv[ci], xv[ci]};
#pragma unroll
                for (int c2 = 0; c2 < 16; ++c2)
                    acc2[c2] = __builtin_elementwise_fma(xv2, wr2[ci * 16 + c2],
                                                         acc2[c2]);
            }
        }
    }

    // ---- two-pass LDS transpose + membrane scan (18432 B) ----
    __shared__ float s_tr[128 * 36];
#pragma unroll
    for (int p = 0; p < 2; ++p) {
        if (p) __syncthreads();                        // pass-1 reads done
#pragma unroll
        for (int j = 0; j < 16; ++j) {                 // write co = 16p+j
            const int c = 16 * p + j;
            s_tr[(j * 8 + wi) * 36 + t] = acc2[c >> 1][c & 1];
        }
        __syncthreads();
        if (tid < 128) {
            const int j2  = tid >> 3;                  // 0..15
            const int wi2 = tid & 7;
            const int co2 = 16 * p + j2;
            const float* rr = s_tr + tid * 36;
            float* op = out + (((b * COUT + co2) * HH + h) * WW + (w0 + wi2)) * TT;
            float mem = 0.0f;
#pragma unroll
            for (int t4 = 0; t4 < TT; t4 += 4) {
                const float4 q = *reinterpret_cast<const float4*>(rr + t4);
                const float cv[4] = {q.x, q.y, q.z, q.w};
                float4 o;
                float* vp = &o.x;
#pragma unroll
                for (int jj = 0; jj < 4; ++jj) {
                    mem = (mem + cv[jj]) * 0.9f;       // two rounded ops — FROZEN
                    const bool sp = (mem >= 0.25f);
                    vp[jj] = sp ? 1.0f : 0.0f;
                    if (sp) mem = 0.0f;
                }
                *reinterpret_cast<float4*>(op + t4) = o;
            }
        }
    }
}

extern "C" void kernel_launch(void* const* d_in, const int* in_sizes, int n_in,
                              void* d_out, int out_size, void* d_ws, size_t ws_size,
                              hipStream_t stream) {
    const float* x   = (const float*)d_in[0];   // 8*16*64*64*32
    const float* wgt = (const float*)d_in[1];   // 32*16*3*3
    float* out = (float*)d_out;                 // 8*32*64*64*32
    float* wT  = (float*)d_ws;                  // 144*32 f32 = 18432 B scratch

    repack_w<<<18, 256, 0, stream>>>(wgt, wT);

    snn_main<<<dim3(4096), dim3(256), 0, stream>>>(x, wT, out);
}